// Round 5
// baseline (253.053 us; speedup 1.0000x reference)
//
#include <hip/hip_runtime.h>
#include <cstdint>
#include <cstddef>

#define NBm 256
#define NAm 96
#define NDm 384
#define NHm 192
#define NFm 96
#define NSm 4
#define NATOMS (NBm*NAm)      /* 24576 */
#define NEe (NATOMS*32)       /* 786432 */
#define CUTOFF_ 5.2f

typedef __attribute__((ext_vector_type(8))) short short8;
typedef __attribute__((ext_vector_type(4))) float float4v;

__device__ __forceinline__ short f2bf(float f){
  union { float f; unsigned u; } v; v.f = f;
  unsigned r = v.u + 0x7FFFu + ((v.u >> 16) & 1u);
  return (short)(r >> 16);
}

// jax.nn.gelu default: tanh approximation
__device__ __forceinline__ float gelu_t(float x){
  float u = 0.7978845608028654f * (x + 0.044715f * x*x*x);
  float e = __expf(-2.0f * fabsf(u));
  float t = (1.0f - e) / (1.0f + e);
  t = (u >= 0.f) ? t : -t;
  return 0.5f * x * (1.0f + t);
}

// ---------- weight prep: f32 -> bf16 transposed [s][col][k]; zeros spc ----------
// R0-verified kernel; only addition: 96 extra trailing blocks zero mrg
// (idx - 405504 in [0, 24576) exactly; weight branches untouched).
#define W1N (NSm*NDm*NHm)   /* 294912 */
#define W2N (NSm*NHm*NFm)   /* 73728 */
#define WNN (NSm*NFm*NFm)   /* 36864 */
#define WTOT (W1N+W2N+WNN)  /* 405504 */
__global__ void k_wprep(const float* __restrict__ W1, const float* __restrict__ W2,
                        const float* __restrict__ Wn,
                        short* __restrict__ W1t, short* __restrict__ W2t,
                        short* __restrict__ Wnt, int* __restrict__ spc,
                        float* __restrict__ mrg){
  if (blockIdx.x == 0 && threadIdx.x < NSm) spc[threadIdx.x] = 0;
  int idx = blockIdx.x*256 + threadIdx.x;
  if (idx < W1N){
    int s = idx / (NDm*NHm); int rem = idx - s*NDm*NHm;
    int k = rem / NHm, c = rem - k*NHm;
    W1t[(s*NHm + c)*NDm + k] = f2bf(W1[idx]);
  } else if (idx < W1N + W2N){
    int j = idx - W1N;
    int s = j / (NHm*NFm); int rem = j - s*NHm*NFm;
    int k = rem / NFm, c = rem - k*NFm;
    W2t[(s*NFm + c)*NHm + k] = f2bf(W2[j]);
  } else if (idx < WTOT){
    int j = idx - W1N - W2N;
    int s = j / (NFm*NFm); int rem = j - s*NFm*NFm;
    int k = rem / NFm, c = rem - k*NFm;
    Wnt[(s*NFm + c)*NFm + k] = f2bf(Wn[j]);
  } else {
    int z = idx - WTOT;          // blocks [1584,1680): z in [0, NATOMS)
    mrg[z] = 0.f;
  }
}

__global__ void k_spcount(const int* __restrict__ sp, int* __restrict__ spc){
  __shared__ int h[NSm];
  int t = threadIdx.x;
  if (t < NSm) h[t] = 0;
  __syncthreads();
  int i = blockIdx.x*256 + t;     // grid = 96 exact
  atomicAdd(&h[sp[i]], 1);
  __syncthreads();
  if (t < NSm) atomicAdd(&spc[t], h[t]);
}

__global__ void k_spscan(const int* __restrict__ spc, int* __restrict__ sps, int* __restrict__ spcur){
  if (threadIdx.x==0 && blockIdx.x==0){
    int r=0;
    for (int s=0;s<NSm;s++){ sps[s]=r; spcur[s]=r; r+=spc[s]; }
    sps[NSm]=r;
  }
}

__global__ void k_spscatter(const int* __restrict__ sp, int* __restrict__ spcur,
                            int* __restrict__ order){
  __shared__ int h[NSm], base[NSm];
  int t = threadIdx.x;
  if (t < NSm) h[t]=0;
  __syncthreads();
  int i = blockIdx.x*256 + t;
  int s = sp[i];
  int lr = atomicAdd(&h[s], 1);
  __syncthreads();
  if (t < NSm) base[t] = atomicAdd(&spcur[t], h[t]);
  __syncthreads();
  order[base[s] + lr] = i;
}

// ---------- fused per-species MLP + epilogue A (R0-verified, verbatim) ----------
__global__ __launch_bounds__(256) void k_mlp(
    const float* __restrict__ X, const int* __restrict__ order,
    const int* __restrict__ sps,
    const short* __restrict__ W1t, const short* __restrict__ W2t,
    const short* __restrict__ Wnt, const float* __restrict__ Wf,
    float* __restrict__ pre, float* __restrict__ nbr_g){
  const int s = blockIdx.y;
  const int s0 = sps[s];
  const int cnt = sps[s+1] - s0;
  const int row0 = blockIdx.x * 64;
  if (row0 >= cnt) return;

  __shared__ short Hs[64][200];     // 25.6 KB
  __shared__ short Is[64][104];     // 13.3 KB
  __shared__ short Ws[19968];       // 39.9 KB staging buffer
  __shared__ int aids[64];

  const int tid = threadIdx.x;
  if (tid < 64){
    int r = row0 + tid;
    aids[tid] = order[s0 + ((r < cnt) ? r : 0)];
  }
  __syncthreads();

  const int wave = tid >> 6, lane = tid & 63;
  const int lrow = lane & 15, quad = lane >> 4;
  const int arow = wave*16 + lrow;
  const float* xrow = X + (size_t)aids[arow]*NDm + quad*8;

  // preload & convert all A fragments (GEMM1) up front
  short8 afs[12];
  #pragma unroll
  for (int kb=0; kb<12; kb++){
    const float* p = xrow + kb*32;
    #pragma unroll
    for (int j=0;j<8;j++) afs[kb][j] = f2bf(p[j]);
  }

  // ---- GEMM1: [64,384]@[384,192]; 4 staged chunks of K=96
  const short* W1s = W1t + (size_t)s*NHm*NDm;
  float4v acc[12];
  #pragma unroll
  for (int i=0;i<12;i++){ acc[i][0]=0.f; acc[i][1]=0.f; acc[i][2]=0.f; acc[i][3]=0.f; }
  for (int kc=0; kc<4; kc++){
    __syncthreads();
    for (int e = tid; e < 192*12; e += 256){   // 192 cols x 12 short8 units
      int c = e / 12, u = e - c*12;
      *(short8*)(&Ws[c*104 + u*8]) = *(const short8*)(W1s + c*NDm + kc*96 + u*8);
    }
    __syncthreads();
    #pragma unroll
    for (int kb3=0; kb3<3; kb3++){
      short8 af = afs[kc*3 + kb3];
      #pragma unroll
      for (int ct=0; ct<12; ct++){
        short8 bfb = *(const short8*)(&Ws[(ct*16 + lrow)*104 + kb3*32 + quad*8]);
        acc[ct] = __builtin_amdgcn_mfma_f32_16x16x32_bf16(af, bfb, acc[ct], 0,0,0);
      }
    }
  }
  // gelu -> Hs (wave-private rows, no barrier)
  #pragma unroll
  for (int ct=0; ct<12; ct++){
    #pragma unroll
    for (int r=0;r<4;r++){
      Hs[wave*16 + quad*4 + r][ct*16 + lrow] = f2bf(gelu_t(acc[ct][r]));
    }
  }

  // ---- GEMM2: [64,192]@[192,96]; stage whole W2 once
  const short* W2s = W2t + (size_t)s*NFm*NHm;
  float4v acc2[6];
  #pragma unroll
  for (int i=0;i<6;i++){ acc2[i][0]=0.f; acc2[i][1]=0.f; acc2[i][2]=0.f; acc2[i][3]=0.f; }
  __syncthreads();
  for (int e = tid; e < 96*24; e += 256){      // 96 cols x 24 short8 units (K=192)
    int c = e / 24, u = e - c*24;
    *(short8*)(&Ws[c*200 + u*8]) = *(const short8*)(W2s + c*NHm + u*8);
  }
  __syncthreads();
  for (int kb=0; kb<6; kb++){
    short8 af2 = *(const short8*)(&Hs[wave*16 + lrow][kb*32 + quad*8]);
    #pragma unroll
    for (int ct=0; ct<6; ct++){
      short8 bfb = *(const short8*)(&Ws[(ct*16 + lrow)*200 + kb*32 + quad*8]);
      acc2[ct] = __builtin_amdgcn_mfma_f32_16x16x32_bf16(af2, bfb, acc2[ct], 0,0,0);
    }
  }
  // internal -> Is (wave-private)
  #pragma unroll
  for (int ct=0; ct<6; ct++){
    #pragma unroll
    for (int r=0;r<4;r++){
      Is[wave*16 + quad*4 + r][ct*16 + lrow] = f2bf(acc2[ct][r]);
    }
  }

  // ---- epilogue A (verified R8): pre = dot(internal_row, Wf[s][0:96])
  {
    float pr[4] = {0.f,0.f,0.f,0.f};
    #pragma unroll
    for (int ct=0; ct<6; ct++){
      float wv = Wf[s*2*NFm + ct*16 + lrow];
      #pragma unroll
      for (int r=0;r<4;r++) pr[r] += acc2[ct][r] * wv;
    }
    #pragma unroll
    for (int m=1; m<16; m<<=1){
      #pragma unroll
      for (int r=0;r<4;r++) pr[r] += __shfl_xor(pr[r], m, 64);
    }
    if (lrow == 0){
      #pragma unroll
      for (int r=0;r<4;r++){
        int row = wave*16 + quad*4 + r;
        if (row0 + row < cnt) pre[aids[row]] = pr[r];
      }
    }
  }

  // ---- GEMM3: [64,96]@[96,96]; stage whole Wn once
  const short* Wns = Wnt + (size_t)s*NFm*NFm;
  float4v acc3[6];
  #pragma unroll
  for (int i=0;i<6;i++){ acc3[i][0]=0.f; acc3[i][1]=0.f; acc3[i][2]=0.f; acc3[i][3]=0.f; }
  __syncthreads();
  for (int e = tid; e < 96*12; e += 256){      // 96 cols x 12 short8 units (K=96)
    int c = e / 12, u = e - c*12;
    *(short8*)(&Ws[c*104 + u*8]) = *(const short8*)(Wns + c*NFm + u*8);
  }
  __syncthreads();
  for (int kb=0; kb<3; kb++){
    short8 af3 = *(const short8*)(&Is[wave*16 + lrow][kb*32 + quad*8]);
    #pragma unroll
    for (int ct=0; ct<6; ct++){
      short8 bfb = *(const short8*)(&Ws[(ct*16 + lrow)*104 + kb*32 + quad*8]);
      acc3[ct] = __builtin_amdgcn_mfma_f32_16x16x32_bf16(af3, bfb, acc3[ct], 0,0,0);
    }
  }
  #pragma unroll
  for (int ct=0; ct<6; ct++){
    #pragma unroll
    for (int r=0;r<4;r++){
      int row = wave*16 + quad*4 + r, col = ct*16 + lrow;
      if (row0 + row < cnt) nbr_g[(size_t)aids[row]*NFm + col] = acc3[ct][r];
    }
  }
}

// ---------- per-atom nd4: one wave per atom, xor-shuffle reduce (R0-verified) ----------
__global__ void k_nd4(const float* __restrict__ nbr, const float* __restrict__ Wf,
                      float* __restrict__ nd4){
  int a = blockIdx.x*4 + (threadIdx.x >> 6);   // grid = NATOMS/4 exact
  int lane = threadIdx.x & 63;
  bool lo = lane < 32;
  const float* np = nbr + (size_t)a*NFm;
  float nv1 = np[lane];
  float nv2 = lo ? np[64+lane] : 0.f;
  const float* w0 = Wf + 0*2*NFm + NFm;
  const float* w1 = Wf + 1*2*NFm + NFm;
  const float* w2 = Wf + 2*2*NFm + NFm;
  const float* w3 = Wf + 3*2*NFm + NFm;
  float n0 = nv1*w0[lane] + (lo ? nv2*w0[64+lane] : 0.f);
  float n1 = nv1*w1[lane] + (lo ? nv2*w1[64+lane] : 0.f);
  float n2 = nv1*w2[lane] + (lo ? nv2*w2[64+lane] : 0.f);
  float n3 = nv1*w3[lane] + (lo ? nv2*w3[64+lane] : 0.f);
  #pragma unroll
  for (int m=1; m<64; m<<=1){
    n0 += __shfl_xor(n0, m, 64);
    n1 += __shfl_xor(n1, m, 64);
    n2 += __shfl_xor(n2, m, 64);
    n3 += __shfl_xor(n3, m, 64);
  }
  if (lane == 0){
    float4v v; v[0]=n0; v[1]=n1; v[2]=n2; v[3]=n3;
    *(float4v*)(nd4 + (size_t)a*4) = v;
  }
}

// ---------- K-edges: direct global atomics (replaces hist/mscan/segscan/
// scatter/accum). mrg[dest] += w * nd4[other][sp[dest]]; grid = NEe/256
__global__ __launch_bounds__(256) void k_edges(const int* __restrict__ ai,
    const float* __restrict__ dist, const float* __restrict__ pref,
    const float* __restrict__ fac, const int* __restrict__ sp,
    const float* __restrict__ nd4, float* __restrict__ mrg){
  int e = blockIdx.x*256 + threadIdx.x;
  int i0 = ai[e];
  int i1 = ai[NEe + e];
  float d = dist[e];
  float p = pref[0], fc = fac[0];
  float x = (CUTOFF_ - d) * (1.0f/CUTOFF_);
  x = fminf(fmaxf(x, 0.f), 1.f);
  float sc = x*x*x*(x*(6.f*x - 15.f) + 10.f);
  float w = p*p * expf(-fc*fc*d) * sc;
  int s0 = sp[i0], s1 = sp[i1];
  float v0 = w * nd4[(size_t)i1*4 + s0];
  float v1 = w * nd4[(size_t)i0*4 + s1];
  atomicAdd(&mrg[i0], v0);
  atomicAdd(&mrg[i1], v1);
}

// ---------- per-molecule charge redistribution + outputs ----------
__global__ __launch_bounds__(128) void k_final(const float* __restrict__ pre,
    const float* __restrict__ mrg, const int* __restrict__ sp,
    const float* __restrict__ tc, float* __restrict__ out){
  __shared__ float red[128];
  int mol = blockIdx.x, t = threadIdx.x;
  float pch = 0.f; int s = 0;
  if (t < NAm){
    s = sp[mol*NAm + t];
    pch = pre[mol*NAm + t] + mrg[mol*NAm + t];
  }
  red[t] = (t < NAm) ? pch : 0.f;
  __syncthreads();
  for (int o=64; o>0; o>>=1){
    if (t < o) red[t] += red[t + o];
    __syncthreads();
  }
  float sum = red[0];
  if (t < NAm){
    out[mol*NAm + t] = (float)s;                       // species as float
    out[NATOMS + mol*NAm + t] = pch + (tc[mol] - sum) * (1.0f/96.0f);  // charges
    out[2*NATOMS + mol*NAm + t] = pch;                 // precharges
  }
}

extern "C" void kernel_launch(void* const* d_in, const int* in_sizes, int n_in,
                              void* d_out, int out_size, void* d_ws, size_t ws_size,
                              hipStream_t stream) {
  const int*   species = (const int*)  d_in[0];
  const float* X       = (const float*)d_in[1];
  const int*   ai      = (const int*)  d_in[2];
  const float* dist    = (const float*)d_in[3];
  const float* tc      = (const float*)d_in[4];
  const float* W1      = (const float*)d_in[5];
  const float* W2      = (const float*)d_in[6];
  const float* Wn      = (const float*)d_in[7];
  const float* Wf      = (const float*)d_in[8];
  const float* pref    = (const float*)d_in[9];
  const float* fac     = (const float*)d_in[10];
  float* out = (float*)d_out;

  char* w = (char*)d_ws;
  auto alloc = [&](size_t bytes)->char*{
    char* p = w; w += (bytes + 255) & ~(size_t)255; return p;
  };
  int*   spc   = (int*)  alloc(64);
  int*   sps   = (int*)  alloc(64);
  int*   spcur = (int*)  alloc(64);
  int*   order = (int*)  alloc((size_t)NATOMS*4);
  float* nd4   = (float*)alloc((size_t)NATOMS*4*4);
  float* pre   = (float*)alloc((size_t)NATOMS*4);
  float* mrg   = (float*)alloc((size_t)NATOMS*4);
  float* nbr   = (float*)alloc((size_t)NATOMS*NFm*4);
  short* W1t   = (short*)alloc((size_t)W1N*2);
  short* W2t   = (short*)alloc((size_t)W2N*2);
  short* Wnt   = (short*)alloc((size_t)WNN*2);

  k_wprep<<<WTOT/256 + NATOMS/256, 256, 0, stream>>>(W1, W2, Wn, W1t, W2t, Wnt, spc, mrg);
  k_spcount<<<NATOMS/256, 256, 0, stream>>>(species, spc);
  k_spscan<<<1, 64, 0, stream>>>(spc, sps, spcur);
  k_spscatter<<<NATOMS/256, 256, 0, stream>>>(species, spcur, order);
  dim3 g(NATOMS/64, NSm);
  k_mlp<<<g, 256, 0, stream>>>(X, order, sps, W1t, W2t, Wnt, Wf, pre, nbr);
  k_nd4<<<NATOMS/4, 256, 0, stream>>>(nbr, Wf, nd4);
  k_edges<<<NEe/256, 256, 0, stream>>>(ai, dist, pref, fac, species, nd4, mrg);
  k_final<<<NBm, 128, 0, stream>>>(pre, mrg, species, tc, out);
}

// Round 7
// 230.513 us; speedup vs baseline: 1.0978x; 1.0978x over previous
//
#include <hip/hip_runtime.h>
#include <cstdint>
#include <cstddef>

#define NBm 256
#define NAm 96
#define NDm 384
#define NHm 192
#define NFm 96
#define NSm 4
#define NATOMS (NBm*NAm)      /* 24576 */
#define NEe (NATOMS*32)       /* 786432 */
#define CUTOFF_ 5.2f
#define MSTRIDE 16            /* floats per atom in mrg: 64B line per atom */
#define MRGN (NATOMS*MSTRIDE) /* 393216 */

typedef __attribute__((ext_vector_type(8))) short short8;
typedef __attribute__((ext_vector_type(4))) float float4v;

__device__ __forceinline__ short f2bf(float f){
  union { float f; unsigned u; } v; v.f = f;
  unsigned r = v.u + 0x7FFFu + ((v.u >> 16) & 1u);
  return (short)(r >> 16);
}

// jax.nn.gelu default: tanh approximation
__device__ __forceinline__ float gelu_t(float x){
  float u = 0.7978845608028654f * (x + 0.044715f * x*x*x);
  float e = __expf(-2.0f * fabsf(u));
  float t = (1.0f - e) / (1.0f + e);
  t = (u >= 0.f) ? t : -t;
  return 0.5f * x * (1.0f + t);
}

// ---------- weight prep: f32 -> bf16 transposed [s][col][k]; zeros spc ----------
// R5-verified kernel; zero-branch now covers padded mrg (MRGN elements).
#define W1N (NSm*NDm*NHm)   /* 294912 */
#define W2N (NSm*NHm*NFm)   /* 73728 */
#define WNN (NSm*NFm*NFm)   /* 36864 */
#define WTOT (W1N+W2N+WNN)  /* 405504 */
__global__ void k_wprep(const float* __restrict__ W1, const float* __restrict__ W2,
                        const float* __restrict__ Wn,
                        short* __restrict__ W1t, short* __restrict__ W2t,
                        short* __restrict__ Wnt, int* __restrict__ spc,
                        float* __restrict__ mrg){
  if (blockIdx.x == 0 && threadIdx.x < NSm) spc[threadIdx.x] = 0;
  int idx = blockIdx.x*256 + threadIdx.x;
  if (idx < W1N){
    int s = idx / (NDm*NHm); int rem = idx - s*NDm*NHm;
    int k = rem / NHm, c = rem - k*NHm;
    W1t[(s*NHm + c)*NDm + k] = f2bf(W1[idx]);
  } else if (idx < W1N + W2N){
    int j = idx - W1N;
    int s = j / (NHm*NFm); int rem = j - s*NHm*NFm;
    int k = rem / NFm, c = rem - k*NFm;
    W2t[(s*NFm + c)*NHm + k] = f2bf(W2[j]);
  } else if (idx < WTOT){
    int j = idx - W1N - W2N;
    int s = j / (NFm*NFm); int rem = j - s*NFm*NFm;
    int k = rem / NFm, c = rem - k*NFm;
    Wnt[(s*NFm + c)*NFm + k] = f2bf(Wn[j]);
  } else {
    int z = idx - WTOT;          // z in [0, MRGN): zero padded accumulator
    mrg[z] = 0.f;
  }
}

__global__ void k_spcount(const int* __restrict__ sp, int* __restrict__ spc){
  __shared__ int h[NSm];
  int t = threadIdx.x;
  if (t < NSm) h[t] = 0;
  __syncthreads();
  int i = blockIdx.x*256 + t;     // grid = 96 exact
  atomicAdd(&h[sp[i]], 1);
  __syncthreads();
  if (t < NSm) atomicAdd(&spc[t], h[t]);
}

__global__ void k_spscan(const int* __restrict__ spc, int* __restrict__ sps, int* __restrict__ spcur){
  if (threadIdx.x==0 && blockIdx.x==0){
    int r=0;
    for (int s=0;s<NSm;s++){ sps[s]=r; spcur[s]=r; r+=spc[s]; }
    sps[NSm]=r;
  }
}

__global__ void k_spscatter(const int* __restrict__ sp, int* __restrict__ spcur,
                            int* __restrict__ order){
  __shared__ int h[NSm], base[NSm];
  int t = threadIdx.x;
  if (t < NSm) h[t]=0;
  __syncthreads();
  int i = blockIdx.x*256 + t;
  int s = sp[i];
  int lr = atomicAdd(&h[s], 1);
  __syncthreads();
  if (t < NSm) base[t] = atomicAdd(&spcur[t], h[t]);
  __syncthreads();
  order[base[s] + lr] = i;
}

// ---------- fused per-species MLP + epilogue A (R5-verified, verbatim) ----------
__global__ __launch_bounds__(256) void k_mlp(
    const float* __restrict__ X, const int* __restrict__ order,
    const int* __restrict__ sps,
    const short* __restrict__ W1t, const short* __restrict__ W2t,
    const short* __restrict__ Wnt, const float* __restrict__ Wf,
    float* __restrict__ pre, float* __restrict__ nbr_g){
  const int s = blockIdx.y;
  const int s0 = sps[s];
  const int cnt = sps[s+1] - s0;
  const int row0 = blockIdx.x * 64;
  if (row0 >= cnt) return;

  __shared__ short Hs[64][200];     // 25.6 KB
  __shared__ short Is[64][104];     // 13.3 KB
  __shared__ short Ws[19968];       // 39.9 KB staging buffer
  __shared__ int aids[64];

  const int tid = threadIdx.x;
  if (tid < 64){
    int r = row0 + tid;
    aids[tid] = order[s0 + ((r < cnt) ? r : 0)];
  }
  __syncthreads();

  const int wave = tid >> 6, lane = tid & 63;
  const int lrow = lane & 15, quad = lane >> 4;
  const int arow = wave*16 + lrow;
  const float* xrow = X + (size_t)aids[arow]*NDm + quad*8;

  // preload & convert all A fragments (GEMM1) up front
  short8 afs[12];
  #pragma unroll
  for (int kb=0; kb<12; kb++){
    const float* p = xrow + kb*32;
    #pragma unroll
    for (int j=0;j<8;j++) afs[kb][j] = f2bf(p[j]);
  }

  // ---- GEMM1: [64,384]@[384,192]; 4 staged chunks of K=96
  const short* W1s = W1t + (size_t)s*NHm*NDm;
  float4v acc[12];
  #pragma unroll
  for (int i=0;i<12;i++){ acc[i][0]=0.f; acc[i][1]=0.f; acc[i][2]=0.f; acc[i][3]=0.f; }
  for (int kc=0; kc<4; kc++){
    __syncthreads();
    for (int e = tid; e < 192*12; e += 256){   // 192 cols x 12 short8 units
      int c = e / 12, u = e - c*12;
      *(short8*)(&Ws[c*104 + u*8]) = *(const short8*)(W1s + c*NDm + kc*96 + u*8);
    }
    __syncthreads();
    #pragma unroll
    for (int kb3=0; kb3<3; kb3++){
      short8 af = afs[kc*3 + kb3];
      #pragma unroll
      for (int ct=0; ct<12; ct++){
        short8 bfb = *(const short8*)(&Ws[(ct*16 + lrow)*104 + kb3*32 + quad*8]);
        acc[ct] = __builtin_amdgcn_mfma_f32_16x16x32_bf16(af, bfb, acc[ct], 0,0,0);
      }
    }
  }
  // gelu -> Hs (wave-private rows, no barrier)
  #pragma unroll
  for (int ct=0; ct<12; ct++){
    #pragma unroll
    for (int r=0;r<4;r++){
      Hs[wave*16 + quad*4 + r][ct*16 + lrow] = f2bf(gelu_t(acc[ct][r]));
    }
  }

  // ---- GEMM2: [64,192]@[192,96]; stage whole W2 once
  const short* W2s = W2t + (size_t)s*NFm*NHm;
  float4v acc2[6];
  #pragma unroll
  for (int i=0;i<6;i++){ acc2[i][0]=0.f; acc2[i][1]=0.f; acc2[i][2]=0.f; acc2[i][3]=0.f; }
  __syncthreads();
  for (int e = tid; e < 96*24; e += 256){      // 96 cols x 24 short8 units (K=192)
    int c = e / 24, u = e - c*24;
    *(short8*)(&Ws[c*200 + u*8]) = *(const short8*)(W2s + c*NHm + u*8);
  }
  __syncthreads();
  for (int kb=0; kb<6; kb++){
    short8 af2 = *(const short8*)(&Hs[wave*16 + lrow][kb*32 + quad*8]);
    #pragma unroll
    for (int ct=0; ct<6; ct++){
      short8 bfb = *(const short8*)(&Ws[(ct*16 + lrow)*200 + kb*32 + quad*8]);
      acc2[ct] = __builtin_amdgcn_mfma_f32_16x16x32_bf16(af2, bfb, acc2[ct], 0,0,0);
    }
  }
  // internal -> Is (wave-private)
  #pragma unroll
  for (int ct=0; ct<6; ct++){
    #pragma unroll
    for (int r=0;r<4;r++){
      Is[wave*16 + quad*4 + r][ct*16 + lrow] = f2bf(acc2[ct][r]);
    }
  }

  // ---- epilogue A (verified): pre = dot(internal_row, Wf[s][0:96])
  {
    float pr[4] = {0.f,0.f,0.f,0.f};
    #pragma unroll
    for (int ct=0; ct<6; ct++){
      float wv = Wf[s*2*NFm + ct*16 + lrow];
      #pragma unroll
      for (int r=0;r<4;r++) pr[r] += acc2[ct][r] * wv;
    }
    #pragma unroll
    for (int m=1; m<16; m<<=1){
      #pragma unroll
      for (int r=0;r<4;r++) pr[r] += __shfl_xor(pr[r], m, 64);
    }
    if (lrow == 0){
      #pragma unroll
      for (int r=0;r<4;r++){
        int row = wave*16 + quad*4 + r;
        if (row0 + row < cnt) pre[aids[row]] = pr[r];
      }
    }
  }

  // ---- GEMM3: [64,96]@[96,96]; stage whole Wn once
  const short* Wns = Wnt + (size_t)s*NFm*NFm;
  float4v acc3[6];
  #pragma unroll
  for (int i=0;i<6;i++){ acc3[i][0]=0.f; acc3[i][1]=0.f; acc3[i][2]=0.f; acc3[i][3]=0.f; }
  __syncthreads();
  for (int e = tid; e < 96*12; e += 256){      // 96 cols x 12 short8 units (K=96)
    int c = e / 12, u = e - c*12;
    *(short8*)(&Ws[c*104 + u*8]) = *(const short8*)(Wns + c*NFm + u*8);
  }
  __syncthreads();
  for (int kb=0; kb<3; kb++){
    short8 af3 = *(const short8*)(&Is[wave*16 + lrow][kb*32 + quad*8]);
    #pragma unroll
    for (int ct=0; ct<6; ct++){
      short8 bfb = *(const short8*)(&Ws[(ct*16 + lrow)*104 + kb*32 + quad*8]);
      acc3[ct] = __builtin_amdgcn_mfma_f32_16x16x32_bf16(af3, bfb, acc3[ct], 0,0,0);
    }
  }
  #pragma unroll
  for (int ct=0; ct<6; ct++){
    #pragma unroll
    for (int r=0;r<4;r++){
      int row = wave*16 + quad*4 + r, col = ct*16 + lrow;
      if (row0 + row < cnt) nbr_g[(size_t)aids[row]*NFm + col] = acc3[ct][r];
    }
  }
}

// ---------- per-atom nd4: one wave per atom, xor-shuffle reduce (R5-verified) ----------
__global__ void k_nd4(const float* __restrict__ nbr, const float* __restrict__ Wf,
                      float* __restrict__ nd4){
  int a = blockIdx.x*4 + (threadIdx.x >> 6);   // grid = NATOMS/4 exact
  int lane = threadIdx.x & 63;
  bool lo = lane < 32;
  const float* np = nbr + (size_t)a*NFm;
  float nv1 = np[lane];
  float nv2 = lo ? np[64+lane] : 0.f;
  const float* w0 = Wf + 0*2*NFm + NFm;
  const float* w1 = Wf + 1*2*NFm + NFm;
  const float* w2 = Wf + 2*2*NFm + NFm;
  const float* w3 = Wf + 3*2*NFm + NFm;
  float n0 = nv1*w0[lane] + (lo ? nv2*w0[64+lane] : 0.f);
  float n1 = nv1*w1[lane] + (lo ? nv2*w1[64+lane] : 0.f);
  float n2 = nv1*w2[lane] + (lo ? nv2*w2[64+lane] : 0.f);
  float n3 = nv1*w3[lane] + (lo ? nv2*w3[64+lane] : 0.f);
  #pragma unroll
  for (int m=1; m<64; m<<=1){
    n0 += __shfl_xor(n0, m, 64);
    n1 += __shfl_xor(n1, m, 64);
    n2 += __shfl_xor(n2, m, 64);
    n3 += __shfl_xor(n3, m, 64);
  }
  if (lane == 0){
    float4v v; v[0]=n0; v[1]=n1; v[2]=n2; v[3]=n3;
    *(float4v*)(nd4 + (size_t)a*4) = v;
  }
}

// ---------- K-edges: global atomics into line-padded mrg ----------
// mrg[dest*MSTRIDE] += w * nd4[other][sp[dest]]; one atom per 64B line
// kills the ~1024-RMW/line serialization measured in R5 (105us, 0.9% VALU).
// Loads de-serialized: sp and full nd4 rows fetched independently, component
// selected in-register. grid = NEe/256
__global__ __launch_bounds__(256) void k_edges(const int* __restrict__ ai,
    const float* __restrict__ dist, const float* __restrict__ pref,
    const float* __restrict__ fac, const int* __restrict__ sp,
    const float* __restrict__ nd4, float* __restrict__ mrg){
  int e = blockIdx.x*256 + threadIdx.x;
  int i0 = ai[e];
  int i1 = ai[NEe + e];
  float d = dist[e];
  int s0 = sp[i0], s1 = sp[i1];
  float4v n1v = *(const float4v*)(nd4 + (size_t)i1*4);
  float4v n0v = *(const float4v*)(nd4 + (size_t)i0*4);
  float p = pref[0], fc = fac[0];
  float x = (CUTOFF_ - d) * (1.0f/CUTOFF_);
  x = fminf(fmaxf(x, 0.f), 1.f);
  float sc = x*x*x*(x*(6.f*x - 15.f) + 10.f);
  float w = p*p * expf(-fc*fc*d) * sc;
  float a1 = (s0 < 2) ? ((s0 == 0) ? n1v[0] : n1v[1]) : ((s0 == 2) ? n1v[2] : n1v[3]);
  float a0 = (s1 < 2) ? ((s1 == 0) ? n0v[0] : n0v[1]) : ((s1 == 2) ? n0v[2] : n0v[3]);
  atomicAdd(&mrg[(size_t)i0*MSTRIDE], w * a1);
  atomicAdd(&mrg[(size_t)i1*MSTRIDE], w * a0);
}

// ---------- per-molecule charge redistribution + outputs ----------
__global__ __launch_bounds__(128) void k_final(const float* __restrict__ pre,
    const float* __restrict__ mrg, const int* __restrict__ sp,
    const float* __restrict__ tc, float* __restrict__ out){
  __shared__ float red[128];
  int mol = blockIdx.x, t = threadIdx.x;
  float pch = 0.f; int s = 0;
  if (t < NAm){
    s = sp[mol*NAm + t];
    pch = pre[mol*NAm + t] + mrg[(size_t)(mol*NAm + t)*MSTRIDE];
  }
  red[t] = (t < NAm) ? pch : 0.f;
  __syncthreads();
  for (int o=64; o>0; o>>=1){
    if (t < o) red[t] += red[t + o];
    __syncthreads();
  }
  float sum = red[0];
  if (t < NAm){
    out[mol*NAm + t] = (float)s;                       // species as float
    out[NATOMS + mol*NAm + t] = pch + (tc[mol] - sum) * (1.0f/96.0f);  // charges
    out[2*NATOMS + mol*NAm + t] = pch;                 // precharges
  }
}

extern "C" void kernel_launch(void* const* d_in, const int* in_sizes, int n_in,
                              void* d_out, int out_size, void* d_ws, size_t ws_size,
                              hipStream_t stream) {
  const int*   species = (const int*)  d_in[0];
  const float* X       = (const float*)d_in[1];
  const int*   ai      = (const int*)  d_in[2];
  const float* dist    = (const float*)d_in[3];
  const float* tc      = (const float*)d_in[4];
  const float* W1      = (const float*)d_in[5];
  const float* W2      = (const float*)d_in[6];
  const float* Wn      = (const float*)d_in[7];
  const float* Wf      = (const float*)d_in[8];
  const float* pref    = (const float*)d_in[9];
  const float* fac     = (const float*)d_in[10];
  float* out = (float*)d_out;

  char* w = (char*)d_ws;
  auto alloc = [&](size_t bytes)->char*{
    char* p = w; w += (bytes + 255) & ~(size_t)255; return p;
  };
  int*   spc   = (int*)  alloc(64);
  int*   sps   = (int*)  alloc(64);
  int*   spcur = (int*)  alloc(64);
  int*   order = (int*)  alloc((size_t)NATOMS*4);
  float* nd4   = (float*)alloc((size_t)NATOMS*4*4);
  float* pre   = (float*)alloc((size_t)NATOMS*4);
  float* mrg   = (float*)alloc((size_t)MRGN*4);
  float* nbr   = (float*)alloc((size_t)NATOMS*NFm*4);
  short* W1t   = (short*)alloc((size_t)W1N*2);
  short* W2t   = (short*)alloc((size_t)W2N*2);
  short* Wnt   = (short*)alloc((size_t)WNN*2);

  k_wprep<<<WTOT/256 + MRGN/256, 256, 0, stream>>>(W1, W2, Wn, W1t, W2t, Wnt, spc, mrg);
  k_spcount<<<NATOMS/256, 256, 0, stream>>>(species, spc);
  k_spscan<<<1, 64, 0, stream>>>(spc, sps, spcur);
  k_spscatter<<<NATOMS/256, 256, 0, stream>>>(species, spcur, order);
  dim3 g(NATOMS/64, NSm);
  k_mlp<<<g, 256, 0, stream>>>(X, order, sps, W1t, W2t, Wnt, Wf, pre, nbr);
  k_nd4<<<NATOMS/4, 256, 0, stream>>>(nbr, Wf, nd4);
  k_edges<<<NEe/256, 256, 0, stream>>>(ai, dist, pref, fac, species, nd4, mrg);
  k_final<<<NBm, 128, 0, stream>>>(pre, mrg, species, tc, out);
}

// Round 8
// 180.099 us; speedup vs baseline: 1.4051x; 1.2799x over previous
//
#include <hip/hip_runtime.h>
#include <cstdint>
#include <cstddef>

#define NBm 256
#define NAm 96
#define NDm 384
#define NHm 192
#define NFm 96
#define NSm 4
#define NATOMS (NBm*NAm)      /* 24576 */
#define NEe (NATOMS*32)       /* 786432 */
#define CUTOFF_ 5.2f
#define PBLK 256              /* edge-accum blocks = partial copies */
#define EPB (NEe/PBLK)        /* 3072 edges per block */

typedef __attribute__((ext_vector_type(8))) short short8;
typedef __attribute__((ext_vector_type(4))) float float4v;

__device__ __forceinline__ short f2bf(float f){
  union { float f; unsigned u; } v; v.f = f;
  unsigned r = v.u + 0x7FFFu + ((v.u >> 16) & 1u);
  return (short)(r >> 16);
}

// jax.nn.gelu default: tanh approximation
__device__ __forceinline__ float gelu_t(float x){
  float u = 0.7978845608028654f * (x + 0.044715f * x*x*x);
  float e = __expf(-2.0f * fabsf(u));
  float t = (1.0f - e) / (1.0f + e);
  t = (u >= 0.f) ? t : -t;
  return 0.5f * x * (1.0f + t);
}

// ---------- weight prep: f32 -> bf16 transposed [s][col][k]; zeros spc ----------
// (R0/R5-verified; mrg-zero branch removed — LDS accumulators need no init)
#define W1N (NSm*NDm*NHm)   /* 294912 */
#define W2N (NSm*NHm*NFm)   /* 73728 */
#define WNN (NSm*NFm*NFm)   /* 36864 */
#define WTOT (W1N+W2N+WNN)  /* 405504 */
__global__ void k_wprep(const float* __restrict__ W1, const float* __restrict__ W2,
                        const float* __restrict__ Wn,
                        short* __restrict__ W1t, short* __restrict__ W2t,
                        short* __restrict__ Wnt, int* __restrict__ spc){
  if (blockIdx.x == 0 && threadIdx.x < NSm) spc[threadIdx.x] = 0;
  int idx = blockIdx.x*256 + threadIdx.x;
  if (idx < W1N){
    int s = idx / (NDm*NHm); int rem = idx - s*NDm*NHm;
    int k = rem / NHm, c = rem - k*NHm;
    W1t[(s*NHm + c)*NDm + k] = f2bf(W1[idx]);
  } else if (idx < W1N + W2N){
    int j = idx - W1N;
    int s = j / (NHm*NFm); int rem = j - s*NHm*NFm;
    int k = rem / NFm, c = rem - k*NFm;
    W2t[(s*NFm + c)*NHm + k] = f2bf(W2[j]);
  } else {
    int j = idx - W1N - W2N;
    int s = j / (NFm*NFm); int rem = j - s*NFm*NFm;
    int k = rem / NFm, c = rem - k*NFm;
    Wnt[(s*NFm + c)*NFm + k] = f2bf(Wn[j]);
  }
}

__global__ void k_spcount(const int* __restrict__ sp, int* __restrict__ spc){
  __shared__ int h[NSm];
  int t = threadIdx.x;
  if (t < NSm) h[t] = 0;
  __syncthreads();
  int i = blockIdx.x*256 + t;     // grid = 96 exact
  atomicAdd(&h[sp[i]], 1);
  __syncthreads();
  if (t < NSm) atomicAdd(&spc[t], h[t]);
}

__global__ void k_spscan(const int* __restrict__ spc, int* __restrict__ sps, int* __restrict__ spcur){
  if (threadIdx.x==0 && blockIdx.x==0){
    int r=0;
    for (int s=0;s<NSm;s++){ sps[s]=r; spcur[s]=r; r+=spc[s]; }
    sps[NSm]=r;
  }
}

__global__ void k_spscatter(const int* __restrict__ sp, int* __restrict__ spcur,
                            int* __restrict__ order){
  __shared__ int h[NSm], base[NSm];
  int t = threadIdx.x;
  if (t < NSm) h[t]=0;
  __syncthreads();
  int i = blockIdx.x*256 + t;
  int s = sp[i];
  int lr = atomicAdd(&h[s], 1);
  __syncthreads();
  if (t < NSm) base[t] = atomicAdd(&spcur[t], h[t]);
  __syncthreads();
  order[base[s] + lr] = i;
}

// ---------- fused per-species MLP + epilogue A (R5-verified, verbatim) ----------
__global__ __launch_bounds__(256) void k_mlp(
    const float* __restrict__ X, const int* __restrict__ order,
    const int* __restrict__ sps,
    const short* __restrict__ W1t, const short* __restrict__ W2t,
    const short* __restrict__ Wnt, const float* __restrict__ Wf,
    float* __restrict__ pre, float* __restrict__ nbr_g){
  const int s = blockIdx.y;
  const int s0 = sps[s];
  const int cnt = sps[s+1] - s0;
  const int row0 = blockIdx.x * 64;
  if (row0 >= cnt) return;

  __shared__ short Hs[64][200];     // 25.6 KB
  __shared__ short Is[64][104];     // 13.3 KB
  __shared__ short Ws[19968];       // 39.9 KB staging buffer
  __shared__ int aids[64];

  const int tid = threadIdx.x;
  if (tid < 64){
    int r = row0 + tid;
    aids[tid] = order[s0 + ((r < cnt) ? r : 0)];
  }
  __syncthreads();

  const int wave = tid >> 6, lane = tid & 63;
  const int lrow = lane & 15, quad = lane >> 4;
  const int arow = wave*16 + lrow;
  const float* xrow = X + (size_t)aids[arow]*NDm + quad*8;

  // preload & convert all A fragments (GEMM1) up front
  short8 afs[12];
  #pragma unroll
  for (int kb=0; kb<12; kb++){
    const float* p = xrow + kb*32;
    #pragma unroll
    for (int j=0;j<8;j++) afs[kb][j] = f2bf(p[j]);
  }

  // ---- GEMM1: [64,384]@[384,192]; 4 staged chunks of K=96
  const short* W1s = W1t + (size_t)s*NHm*NDm;
  float4v acc[12];
  #pragma unroll
  for (int i=0;i<12;i++){ acc[i][0]=0.f; acc[i][1]=0.f; acc[i][2]=0.f; acc[i][3]=0.f; }
  for (int kc=0; kc<4; kc++){
    __syncthreads();
    for (int e = tid; e < 192*12; e += 256){   // 192 cols x 12 short8 units
      int c = e / 12, u = e - c*12;
      *(short8*)(&Ws[c*104 + u*8]) = *(const short8*)(W1s + c*NDm + kc*96 + u*8);
    }
    __syncthreads();
    #pragma unroll
    for (int kb3=0; kb3<3; kb3++){
      short8 af = afs[kc*3 + kb3];
      #pragma unroll
      for (int ct=0; ct<12; ct++){
        short8 bfb = *(const short8*)(&Ws[(ct*16 + lrow)*104 + kb3*32 + quad*8]);
        acc[ct] = __builtin_amdgcn_mfma_f32_16x16x32_bf16(af, bfb, acc[ct], 0,0,0);
      }
    }
  }
  // gelu -> Hs (wave-private rows, no barrier)
  #pragma unroll
  for (int ct=0; ct<12; ct++){
    #pragma unroll
    for (int r=0;r<4;r++){
      Hs[wave*16 + quad*4 + r][ct*16 + lrow] = f2bf(gelu_t(acc[ct][r]));
    }
  }

  // ---- GEMM2: [64,192]@[192,96]; stage whole W2 once
  const short* W2s = W2t + (size_t)s*NFm*NHm;
  float4v acc2[6];
  #pragma unroll
  for (int i=0;i<6;i++){ acc2[i][0]=0.f; acc2[i][1]=0.f; acc2[i][2]=0.f; acc2[i][3]=0.f; }
  __syncthreads();
  for (int e = tid; e < 96*24; e += 256){      // 96 cols x 24 short8 units (K=192)
    int c = e / 24, u = e - c*24;
    *(short8*)(&Ws[c*200 + u*8]) = *(const short8*)(W2s + c*NHm + u*8);
  }
  __syncthreads();
  for (int kb=0; kb<6; kb++){
    short8 af2 = *(const short8*)(&Hs[wave*16 + lrow][kb*32 + quad*8]);
    #pragma unroll
    for (int ct=0; ct<6; ct++){
      short8 bfb = *(const short8*)(&Ws[(ct*16 + lrow)*200 + kb*32 + quad*8]);
      acc2[ct] = __builtin_amdgcn_mfma_f32_16x16x32_bf16(af2, bfb, acc2[ct], 0,0,0);
    }
  }
  // internal -> Is (wave-private)
  #pragma unroll
  for (int ct=0; ct<6; ct++){
    #pragma unroll
    for (int r=0;r<4;r++){
      Is[wave*16 + quad*4 + r][ct*16 + lrow] = f2bf(acc2[ct][r]);
    }
  }

  // ---- epilogue A (verified): pre = dot(internal_row, Wf[s][0:96])
  {
    float pr[4] = {0.f,0.f,0.f,0.f};
    #pragma unroll
    for (int ct=0; ct<6; ct++){
      float wv = Wf[s*2*NFm + ct*16 + lrow];
      #pragma unroll
      for (int r=0;r<4;r++) pr[r] += acc2[ct][r] * wv;
    }
    #pragma unroll
    for (int m=1; m<16; m<<=1){
      #pragma unroll
      for (int r=0;r<4;r++) pr[r] += __shfl_xor(pr[r], m, 64);
    }
    if (lrow == 0){
      #pragma unroll
      for (int r=0;r<4;r++){
        int row = wave*16 + quad*4 + r;
        if (row0 + row < cnt) pre[aids[row]] = pr[r];
      }
    }
  }

  // ---- GEMM3: [64,96]@[96,96]; stage whole Wn once
  const short* Wns = Wnt + (size_t)s*NFm*NFm;
  float4v acc3[6];
  #pragma unroll
  for (int i=0;i<6;i++){ acc3[i][0]=0.f; acc3[i][1]=0.f; acc3[i][2]=0.f; acc3[i][3]=0.f; }
  __syncthreads();
  for (int e = tid; e < 96*12; e += 256){      // 96 cols x 12 short8 units (K=96)
    int c = e / 12, u = e - c*12;
    *(short8*)(&Ws[c*104 + u*8]) = *(const short8*)(Wns + c*NFm + u*8);
  }
  __syncthreads();
  for (int kb=0; kb<3; kb++){
    short8 af3 = *(const short8*)(&Is[wave*16 + lrow][kb*32 + quad*8]);
    #pragma unroll
    for (int ct=0; ct<6; ct++){
      short8 bfb = *(const short8*)(&Ws[(ct*16 + lrow)*104 + kb*32 + quad*8]);
      acc3[ct] = __builtin_amdgcn_mfma_f32_16x16x32_bf16(af3, bfb, acc3[ct], 0,0,0);
    }
  }
  #pragma unroll
  for (int ct=0; ct<6; ct++){
    #pragma unroll
    for (int r=0;r<4;r++){
      int row = wave*16 + quad*4 + r, col = ct*16 + lrow;
      if (row0 + row < cnt) nbr_g[(size_t)aids[row]*NFm + col] = acc3[ct][r];
    }
  }
}

// ---------- per-atom nd4: one wave per atom, xor-shuffle reduce (R5-verified) ----------
__global__ void k_nd4(const float* __restrict__ nbr, const float* __restrict__ Wf,
                      float* __restrict__ nd4){
  int a = blockIdx.x*4 + (threadIdx.x >> 6);   // grid = NATOMS/4 exact
  int lane = threadIdx.x & 63;
  bool lo = lane < 32;
  const float* np = nbr + (size_t)a*NFm;
  float nv1 = np[lane];
  float nv2 = lo ? np[64+lane] : 0.f;
  const float* w0 = Wf + 0*2*NFm + NFm;
  const float* w1 = Wf + 1*2*NFm + NFm;
  const float* w2 = Wf + 2*2*NFm + NFm;
  const float* w3 = Wf + 3*2*NFm + NFm;
  float n0 = nv1*w0[lane] + (lo ? nv2*w0[64+lane] : 0.f);
  float n1 = nv1*w1[lane] + (lo ? nv2*w1[64+lane] : 0.f);
  float n2 = nv1*w2[lane] + (lo ? nv2*w2[64+lane] : 0.f);
  float n3 = nv1*w3[lane] + (lo ? nv2*w3[64+lane] : 0.f);
  #pragma unroll
  for (int m=1; m<64; m<<=1){
    n0 += __shfl_xor(n0, m, 64);
    n1 += __shfl_xor(n1, m, 64);
    n2 += __shfl_xor(n2, m, 64);
    n3 += __shfl_xor(n3, m, 64);
  }
  if (lane == 0){
    float4v v; v[0]=n0; v[1]=n1; v[2]=n2; v[3]=n3;
    *(float4v*)(nd4 + (size_t)a*4) = v;
  }
}

// ---------- K-eacc: edge accumulate via full-mrg LDS privatization ----------
// Each block holds the ENTIRE 96KB mrg array in LDS (160KB/CU), LDS-atomicAdds
// both endpoints of its 3072 edges, then flushes a coalesced partial copy.
// Replaces the 82.7us device-atomic k_edges (memory-side RMW throughput-bound
// at ~19G atomics/s, R7 counters). Zero global atomics.
__global__ __launch_bounds__(1024) void k_eacc(const int* __restrict__ ai,
    const float* __restrict__ dist, const float* __restrict__ pref,
    const float* __restrict__ fac, const int* __restrict__ sp,
    const float* __restrict__ nd4, float* __restrict__ part){
  __shared__ float acc[NATOMS];    // 96 KB
  const int t = threadIdx.x, b = blockIdx.x;
  #pragma unroll
  for (int k=0;k<NATOMS/1024;k++) acc[k*1024 + t] = 0.f;   // 24 stores
  __syncthreads();
  const float p = pref[0], fc = fac[0];
  const int base = b*EPB;
  #pragma unroll
  for (int k=0;k<EPB/1024;k++){    // 3 edges/thread, coalesced
    int e = base + k*1024 + t;
    int i0 = ai[e];
    int i1 = ai[NEe + e];
    float d = dist[e];
    int s0 = sp[i0], s1 = sp[i1];
    float4v n1v = *(const float4v*)(nd4 + (size_t)i1*4);
    float4v n0v = *(const float4v*)(nd4 + (size_t)i0*4);
    float x = (CUTOFF_ - d) * (1.0f/CUTOFF_);
    x = fminf(fmaxf(x, 0.f), 1.f);
    float sc = x*x*x*(x*(6.f*x - 15.f) + 10.f);
    float w = p*p * expf(-fc*fc*d) * sc;
    float a1 = (s0 < 2) ? ((s0 == 0) ? n1v[0] : n1v[1]) : ((s0 == 2) ? n1v[2] : n1v[3]);
    float a0 = (s1 < 2) ? ((s1 == 0) ? n0v[0] : n0v[1]) : ((s1 == 2) ? n0v[2] : n0v[3]);
    atomicAdd(&acc[i0], w * a1);
    atomicAdd(&acc[i1], w * a0);
  }
  __syncthreads();
  float* dst = part + (size_t)b*NATOMS;
  for (int k=t; k<NATOMS/4; k+=1024){            // 6 x float4 stores, coalesced
    *(float4v*)(dst + k*4) = *(const float4v*)(&acc[k*4]);
  }
}

// ---------- per-molecule: 256-partial reduce + charge redistribution ----------
__global__ __launch_bounds__(128) void k_final(const float* __restrict__ pre,
    const float* __restrict__ part, const int* __restrict__ sp,
    const float* __restrict__ tc, float* __restrict__ out){
  __shared__ float red[128];
  int mol = blockIdx.x, t = threadIdx.x;
  float pch = 0.f; int s = 0;
  if (t < NAm){
    int a = mol*NAm + t;
    s = sp[a];
    float m = 0.f;
    #pragma unroll 8
    for (int b=0; b<PBLK; b++) m += part[(size_t)b*NATOMS + a];
    pch = pre[a] + m;
  }
  red[t] = (t < NAm) ? pch : 0.f;
  __syncthreads();
  for (int o=64; o>0; o>>=1){
    if (t < o) red[t] += red[t + o];
    __syncthreads();
  }
  float sum = red[0];
  if (t < NAm){
    out[mol*NAm + t] = (float)s;                       // species as float
    out[NATOMS + mol*NAm + t] = pch + (tc[mol] - sum) * (1.0f/96.0f);  // charges
    out[2*NATOMS + mol*NAm + t] = pch;                 // precharges
  }
}

extern "C" void kernel_launch(void* const* d_in, const int* in_sizes, int n_in,
                              void* d_out, int out_size, void* d_ws, size_t ws_size,
                              hipStream_t stream) {
  const int*   species = (const int*)  d_in[0];
  const float* X       = (const float*)d_in[1];
  const int*   ai      = (const int*)  d_in[2];
  const float* dist    = (const float*)d_in[3];
  const float* tc      = (const float*)d_in[4];
  const float* W1      = (const float*)d_in[5];
  const float* W2      = (const float*)d_in[6];
  const float* Wn      = (const float*)d_in[7];
  const float* Wf      = (const float*)d_in[8];
  const float* pref    = (const float*)d_in[9];
  const float* fac     = (const float*)d_in[10];
  float* out = (float*)d_out;

  char* w = (char*)d_ws;
  auto alloc = [&](size_t bytes)->char*{
    char* p = w; w += (bytes + 255) & ~(size_t)255; return p;
  };
  int*   spc   = (int*)  alloc(64);
  int*   sps   = (int*)  alloc(64);
  int*   spcur = (int*)  alloc(64);
  int*   order = (int*)  alloc((size_t)NATOMS*4);
  float* nd4   = (float*)alloc((size_t)NATOMS*4*4);
  float* pre   = (float*)alloc((size_t)NATOMS*4);
  float* nbr   = (float*)alloc((size_t)NATOMS*NFm*4);
  float* part  = (float*)alloc((size_t)PBLK*NATOMS*4);   // 25.2 MB
  short* W1t   = (short*)alloc((size_t)W1N*2);
  short* W2t   = (short*)alloc((size_t)W2N*2);
  short* Wnt   = (short*)alloc((size_t)WNN*2);

  k_wprep<<<WTOT/256, 256, 0, stream>>>(W1, W2, Wn, W1t, W2t, Wnt, spc);
  k_spcount<<<NATOMS/256, 256, 0, stream>>>(species, spc);
  k_spscan<<<1, 64, 0, stream>>>(spc, sps, spcur);
  k_spscatter<<<NATOMS/256, 256, 0, stream>>>(species, spcur, order);
  dim3 g(NATOMS/64, NSm);
  k_mlp<<<g, 256, 0, stream>>>(X, order, sps, W1t, W2t, Wnt, Wf, pre, nbr);
  k_nd4<<<NATOMS/4, 256, 0, stream>>>(nbr, Wf, nd4);
  k_eacc<<<PBLK, 1024, 0, stream>>>(ai, dist, pref, fac, species, nd4, part);
  k_final<<<NBm, 128, 0, stream>>>(pre, part, species, tc, out);
}

// Round 12
// 172.608 us; speedup vs baseline: 1.4661x; 1.0434x over previous
//
#include <hip/hip_runtime.h>
#include <cstdint>
#include <cstddef>

#define NBm 256
#define NAm 96
#define NDm 384
#define NHm 192
#define NFm 96
#define NSm 4
#define NATOMS (NBm*NAm)      /* 24576 */
#define NEe (NATOMS*32)       /* 786432 */
#define CUTOFF_ 5.2f
#define PBLK 256              /* edge-accum blocks = partial copies */
#define EPB (NEe/PBLK)        /* 3072 edges per block */

typedef __attribute__((ext_vector_type(8))) short short8;
typedef __attribute__((ext_vector_type(4))) float float4v;

__device__ __forceinline__ short f2bf(float f){
  union { float f; unsigned u; } v; v.f = f;
  unsigned r = v.u + 0x7FFFu + ((v.u >> 16) & 1u);
  return (short)(r >> 16);
}

// jax.nn.gelu default: tanh approximation
__device__ __forceinline__ float gelu_t(float x){
  float u = 0.7978845608028654f * (x + 0.044715f * x*x*x);
  float e = __expf(-2.0f * fabsf(u));
  float t = (1.0f - e) / (1.0f + e);
  t = (u >= 0.f) ? t : -t;
  return 0.5f * x * (1.0f + t);
}

// ---------- weight prep: f32 -> bf16 transposed [s][col][k]; zeros spc ----------
#define W1N (NSm*NDm*NHm)   /* 294912 */
#define W2N (NSm*NHm*NFm)   /* 73728 */
#define WNN (NSm*NFm*NFm)   /* 36864 */
#define WTOT (W1N+W2N+WNN)  /* 405504 */
__global__ void k_wprep(const float* __restrict__ W1, const float* __restrict__ W2,
                        const float* __restrict__ Wn,
                        short* __restrict__ W1t, short* __restrict__ W2t,
                        short* __restrict__ Wnt, int* __restrict__ spc){
  if (blockIdx.x == 0 && threadIdx.x < NSm) spc[threadIdx.x] = 0;
  int idx = blockIdx.x*256 + threadIdx.x;
  if (idx < W1N){
    int s = idx / (NDm*NHm); int rem = idx - s*NDm*NHm;
    int k = rem / NHm, c = rem - k*NHm;
    W1t[(s*NHm + c)*NDm + k] = f2bf(W1[idx]);
  } else if (idx < W1N + W2N){
    int j = idx - W1N;
    int s = j / (NHm*NFm); int rem = j - s*NHm*NFm;
    int k = rem / NFm, c = rem - k*NFm;
    W2t[(s*NFm + c)*NHm + k] = f2bf(W2[j]);
  } else {
    int j = idx - W1N - W2N;
    int s = j / (NFm*NFm); int rem = j - s*NFm*NFm;
    int k = rem / NFm, c = rem - k*NFm;
    Wnt[(s*NFm + c)*NFm + k] = f2bf(Wn[j]);
  }
}

__global__ void k_spcount(const int* __restrict__ sp, int* __restrict__ spc){
  __shared__ int h[NSm];
  int t = threadIdx.x;
  if (t < NSm) h[t] = 0;
  __syncthreads();
  int i = blockIdx.x*256 + t;     // grid = 96 exact
  atomicAdd(&h[sp[i]], 1);
  __syncthreads();
  if (t < NSm) atomicAdd(&spc[t], h[t]);
}

__global__ void k_spscan(const int* __restrict__ spc, int* __restrict__ sps, int* __restrict__ spcur){
  if (threadIdx.x==0 && blockIdx.x==0){
    int r=0;
    for (int s=0;s<NSm;s++){ sps[s]=r; spcur[s]=r; r+=spc[s]; }
    sps[NSm]=r;
  }
}

__global__ void k_spscatter(const int* __restrict__ sp, int* __restrict__ spcur,
                            int* __restrict__ order){
  __shared__ int h[NSm], base[NSm];
  int t = threadIdx.x;
  if (t < NSm) h[t]=0;
  __syncthreads();
  int i = blockIdx.x*256 + t;
  int s = sp[i];
  int lr = atomicAdd(&h[s], 1);
  __syncthreads();
  if (t < NSm) base[t] = atomicAdd(&spcur[t], h[t]);
  __syncthreads();
  order[base[s] + lr] = i;
}

// ---------- fused per-species MLP + epilogue A + LDS-staged nd4 epilogue ----------
// GEMMs and epilogue A byte-identical to R8-verified kernel. The nd4 epilogue
// stages acc3 into LDS with the EXACT index mapping verified by R8's nbr_g
// global write, then computes nd4 with a trivially-correct per-thread serial
// dot. No shfl in this epilogue (the shfl variant failed twice: R1, R9).
__global__ __launch_bounds__(256) void k_mlp(
    const float* __restrict__ X, const int* __restrict__ order,
    const int* __restrict__ sps,
    const short* __restrict__ W1t, const short* __restrict__ W2t,
    const short* __restrict__ Wnt, const float* __restrict__ Wf,
    float* __restrict__ pre, float* __restrict__ nd4){
  const int s = blockIdx.y;
  const int s0 = sps[s];
  const int cnt = sps[s+1] - s0;
  const int row0 = blockIdx.x * 64;
  if (row0 >= cnt) return;

  __shared__ short Hs[64][200];     // 25.6 KB
  __shared__ short Is[64][104];     // 13.3 KB
  __shared__ short Ws[19968];       // 39.9 KB staging buffer (aliased as NL below)
  __shared__ int aids[64];

  const int tid = threadIdx.x;
  if (tid < 64){
    int r = row0 + tid;
    aids[tid] = order[s0 + ((r < cnt) ? r : 0)];
  }
  __syncthreads();

  const int wave = tid >> 6, lane = tid & 63;
  const int lrow = lane & 15, quad = lane >> 4;
  const int arow = wave*16 + lrow;
  const float* xrow = X + (size_t)aids[arow]*NDm + quad*8;

  // preload & convert all A fragments (GEMM1) up front
  short8 afs[12];
  #pragma unroll
  for (int kb=0; kb<12; kb++){
    const float* p = xrow + kb*32;
    #pragma unroll
    for (int j=0;j<8;j++) afs[kb][j] = f2bf(p[j]);
  }

  // ---- GEMM1: [64,384]@[384,192]; 4 staged chunks of K=96
  const short* W1s = W1t + (size_t)s*NHm*NDm;
  float4v acc[12];
  #pragma unroll
  for (int i=0;i<12;i++){ acc[i][0]=0.f; acc[i][1]=0.f; acc[i][2]=0.f; acc[i][3]=0.f; }
  for (int kc=0; kc<4; kc++){
    __syncthreads();
    for (int e = tid; e < 192*12; e += 256){   // 192 cols x 12 short8 units
      int c = e / 12, u = e - c*12;
      *(short8*)(&Ws[c*104 + u*8]) = *(const short8*)(W1s + c*NDm + kc*96 + u*8);
    }
    __syncthreads();
    #pragma unroll
    for (int kb3=0; kb3<3; kb3++){
      short8 af = afs[kc*3 + kb3];
      #pragma unroll
      for (int ct=0; ct<12; ct++){
        short8 bfb = *(const short8*)(&Ws[(ct*16 + lrow)*104 + kb3*32 + quad*8]);
        acc[ct] = __builtin_amdgcn_mfma_f32_16x16x32_bf16(af, bfb, acc[ct], 0,0,0);
      }
    }
  }
  // gelu -> Hs (wave-private rows, no barrier)
  #pragma unroll
  for (int ct=0; ct<12; ct++){
    #pragma unroll
    for (int r=0;r<4;r++){
      Hs[wave*16 + quad*4 + r][ct*16 + lrow] = f2bf(gelu_t(acc[ct][r]));
    }
  }

  // ---- GEMM2: [64,192]@[192,96]; stage whole W2 once
  const short* W2s = W2t + (size_t)s*NFm*NHm;
  float4v acc2[6];
  #pragma unroll
  for (int i=0;i<6;i++){ acc2[i][0]=0.f; acc2[i][1]=0.f; acc2[i][2]=0.f; acc2[i][3]=0.f; }
  __syncthreads();
  for (int e = tid; e < 96*24; e += 256){      // 96 cols x 24 short8 units (K=192)
    int c = e / 24, u = e - c*24;
    *(short8*)(&Ws[c*200 + u*8]) = *(const short8*)(W2s + c*NHm + u*8);
  }
  __syncthreads();
  for (int kb=0; kb<6; kb++){
    short8 af2 = *(const short8*)(&Hs[wave*16 + lrow][kb*32 + quad*8]);
    #pragma unroll
    for (int ct=0; ct<6; ct++){
      short8 bfb = *(const short8*)(&Ws[(ct*16 + lrow)*200 + kb*32 + quad*8]);
      acc2[ct] = __builtin_amdgcn_mfma_f32_16x16x32_bf16(af2, bfb, acc2[ct], 0,0,0);
    }
  }
  // internal -> Is (wave-private)
  #pragma unroll
  for (int ct=0; ct<6; ct++){
    #pragma unroll
    for (int r=0;r<4;r++){
      Is[wave*16 + quad*4 + r][ct*16 + lrow] = f2bf(acc2[ct][r]);
    }
  }

  // ---- epilogue A (verified): pre = dot(internal_row, Wf[s][0:96])
  {
    float pr[4] = {0.f,0.f,0.f,0.f};
    #pragma unroll
    for (int ct=0; ct<6; ct++){
      float wv = Wf[s*2*NFm + ct*16 + lrow];
      #pragma unroll
      for (int r=0;r<4;r++) pr[r] += acc2[ct][r] * wv;
    }
    #pragma unroll
    for (int m=1; m<16; m<<=1){
      #pragma unroll
      for (int r=0;r<4;r++) pr[r] += __shfl_xor(pr[r], m, 64);
    }
    if (lrow == 0){
      #pragma unroll
      for (int r=0;r<4;r++){
        int row = wave*16 + quad*4 + r;
        if (row0 + row < cnt) pre[aids[row]] = pr[r];
      }
    }
  }

  // ---- GEMM3: [64,96]@[96,96]; stage whole Wn once
  const short* Wns = Wnt + (size_t)s*NFm*NFm;
  float4v acc3[6];
  #pragma unroll
  for (int i=0;i<6;i++){ acc3[i][0]=0.f; acc3[i][1]=0.f; acc3[i][2]=0.f; acc3[i][3]=0.f; }
  __syncthreads();
  for (int e = tid; e < 96*12; e += 256){      // 96 cols x 12 short8 units (K=96)
    int c = e / 12, u = e - c*12;
    *(short8*)(&Ws[c*104 + u*8]) = *(const short8*)(Wns + c*NFm + u*8);
  }
  __syncthreads();
  for (int kb=0; kb<3; kb++){
    short8 af3 = *(const short8*)(&Is[wave*16 + lrow][kb*32 + quad*8]);
    #pragma unroll
    for (int ct=0; ct<6; ct++){
      short8 bfb = *(const short8*)(&Ws[(ct*16 + lrow)*104 + kb*32 + quad*8]);
      acc3[ct] = __builtin_amdgcn_mfma_f32_16x16x32_bf16(af3, bfb, acc3[ct], 0,0,0);
    }
  }

  // ---- epilogue B (LDS-staged, replaces k_nd4): nd4[a][t2] = dot(nbr_row, Wf[t2][F:2F])
  {
    float* NL = (float*)Ws;            // Ws dead after GEMM3 reads (barrier below)
    __syncthreads();                   // all waves done reading Ws
    // stage acc3 with the EXACT mapping verified by R8's nbr_g write
    #pragma unroll
    for (int ct=0; ct<6; ct++){
      #pragma unroll
      for (int r=0;r<4;r++){
        NL[(wave*16 + quad*4 + r)*97 + ct*16 + lrow] = acc3[ct][r];
      }
    }
    __syncthreads();
    // trivially-correct serial dot: thread t -> (row = t>>2, t2 = t&3)
    int row = tid >> 2, t2 = tid & 3;
    if (row0 + row < cnt){
      const float* wfp = Wf + t2*2*NFm + NFm;
      const float* nlr = NL + row*97;
      float a4 = 0.f;
      #pragma unroll 8
      for (int j=0;j<NFm;j++) a4 += nlr[j] * wfp[j];
      nd4[(size_t)aids[row]*4 + t2] = a4;
    }
  }
}

// ---------- K-eacc: edge accumulate via full-mrg LDS privatization (R8-verified) ----------
__global__ __launch_bounds__(1024) void k_eacc(const int* __restrict__ ai,
    const float* __restrict__ dist, const float* __restrict__ pref,
    const float* __restrict__ fac, const int* __restrict__ sp,
    const float* __restrict__ nd4, float* __restrict__ part){
  __shared__ float acc[NATOMS];    // 96 KB
  const int t = threadIdx.x, b = blockIdx.x;
  #pragma unroll
  for (int k=0;k<NATOMS/1024;k++) acc[k*1024 + t] = 0.f;   // 24 stores
  __syncthreads();
  const float p = pref[0], fc = fac[0];
  const int base = b*EPB;
  #pragma unroll
  for (int k=0;k<EPB/1024;k++){    // 3 edges/thread, coalesced
    int e = base + k*1024 + t;
    int i0 = ai[e];
    int i1 = ai[NEe + e];
    float d = dist[e];
    int s0 = sp[i0], s1 = sp[i1];
    float4v n1v = *(const float4v*)(nd4 + (size_t)i1*4);
    float4v n0v = *(const float4v*)(nd4 + (size_t)i0*4);
    float x = (CUTOFF_ - d) * (1.0f/CUTOFF_);
    x = fminf(fmaxf(x, 0.f), 1.f);
    float sc = x*x*x*(x*(6.f*x - 15.f) + 10.f);
    float w = p*p * expf(-fc*fc*d) * sc;
    float a1 = (s0 < 2) ? ((s0 == 0) ? n1v[0] : n1v[1]) : ((s0 == 2) ? n1v[2] : n1v[3]);
    float a0 = (s1 < 2) ? ((s1 == 0) ? n0v[0] : n0v[1]) : ((s1 == 2) ? n0v[2] : n0v[3]);
    atomicAdd(&acc[i0], w * a1);
    atomicAdd(&acc[i1], w * a0);
  }
  __syncthreads();
  float* dst = part + (size_t)b*NATOMS;
  for (int k=t; k<NATOMS/4; k+=1024){            // 6 x float4 stores, coalesced
    *(float4v*)(dst + k*4) = *(const float4v*)(&acc[k*4]);
  }
}

// ---------- per-molecule: 256-partial reduce + charge redistribution (R8-verified) ----------
__global__ __launch_bounds__(128) void k_final(const float* __restrict__ pre,
    const float* __restrict__ part, const int* __restrict__ sp,
    const float* __restrict__ tc, float* __restrict__ out){
  __shared__ float red[128];
  int mol = blockIdx.x, t = threadIdx.x;
  float pch = 0.f; int s = 0;
  if (t < NAm){
    int a = mol*NAm + t;
    s = sp[a];
    float m = 0.f;
    #pragma unroll 8
    for (int b=0; b<PBLK; b++) m += part[(size_t)b*NATOMS + a];
    pch = pre[a] + m;
  }
  red[t] = (t < NAm) ? pch : 0.f;
  __syncthreads();
  for (int o=64; o>0; o>>=1){
    if (t < o) red[t] += red[t + o];
    __syncthreads();
  }
  float sum = red[0];
  if (t < NAm){
    out[mol*NAm + t] = (float)s;                       // species as float
    out[NATOMS + mol*NAm + t] = pch + (tc[mol] - sum) * (1.0f/96.0f);  // charges
    out[2*NATOMS + mol*NAm + t] = pch;                 // precharges
  }
}

extern "C" void kernel_launch(void* const* d_in, const int* in_sizes, int n_in,
                              void* d_out, int out_size, void* d_ws, size_t ws_size,
                              hipStream_t stream) {
  const int*   species = (const int*)  d_in[0];
  const float* X       = (const float*)d_in[1];
  const int*   ai      = (const int*)  d_in[2];
  const float* dist    = (const float*)d_in[3];
  const float* tc      = (const float*)d_in[4];
  const float* W1      = (const float*)d_in[5];
  const float* W2      = (const float*)d_in[6];
  const float* Wn      = (const float*)d_in[7];
  const float* Wf      = (const float*)d_in[8];
  const float* pref    = (const float*)d_in[9];
  const float* fac     = (const float*)d_in[10];
  float* out = (float*)d_out;

  char* w = (char*)d_ws;
  auto alloc = [&](size_t bytes)->char*{
    char* p = w; w += (bytes + 255) & ~(size_t)255; return p;
  };
  int*   spc   = (int*)  alloc(64);
  int*   sps   = (int*)  alloc(64);
  int*   spcur = (int*)  alloc(64);
  int*   order = (int*)  alloc((size_t)NATOMS*4);
  float* nd4   = (float*)alloc((size_t)NATOMS*4*4);
  float* pre   = (float*)alloc((size_t)NATOMS*4);
  float* part  = (float*)alloc((size_t)PBLK*NATOMS*4);   // 25.2 MB
  short* W1t   = (short*)alloc((size_t)W1N*2);
  short* W2t   = (short*)alloc((size_t)W2N*2);
  short* Wnt   = (short*)alloc((size_t)WNN*2);

  k_wprep<<<WTOT/256, 256, 0, stream>>>(W1, W2, Wn, W1t, W2t, Wnt, spc);
  k_spcount<<<NATOMS/256, 256, 0, stream>>>(species, spc);
  k_spscan<<<1, 64, 0, stream>>>(spc, sps, spcur);
  k_spscatter<<<NATOMS/256, 256, 0, stream>>>(species, spcur, order);
  dim3 g(NATOMS/64, NSm);
  k_mlp<<<g, 256, 0, stream>>>(X, order, sps, W1t, W2t, Wnt, Wf, pre, nd4);
  k_eacc<<<PBLK, 1024, 0, stream>>>(ai, dist, pref, fac, species, nd4, part);
  k_final<<<NBm, 128, 0, stream>>>(pre, part, species, tc, out);
}

// Round 14
// 169.466 us; speedup vs baseline: 1.4932x; 1.0185x over previous
//
#include <hip/hip_runtime.h>
#include <cstdint>
#include <cstddef>

#define NBm 256
#define NAm 96
#define NDm 384
#define NHm 192
#define NFm 96
#define NSm 4
#define NATOMS (NBm*NAm)      /* 24576 */
#define NEe (NATOMS*32)       /* 786432 */
#define CUTOFF_ 5.2f
#define PBLK 256              /* edge-accum blocks = partial copies */
#define EPB (NEe/PBLK)        /* 3072 edges per block */
#define HBLK 96               /* NATOMS/256 hist blocks */

typedef __attribute__((ext_vector_type(8))) short short8;
typedef __attribute__((ext_vector_type(4))) float float4v;

__device__ __forceinline__ short f2bf(float f){
  union { float f; unsigned u; } v; v.f = f;
  unsigned r = v.u + 0x7FFFu + ((v.u >> 16) & 1u);
  return (short)(r >> 16);
}

// jax.nn.gelu default: tanh approximation
__device__ __forceinline__ float gelu_t(float x){
  float u = 0.7978845608028654f * (x + 0.044715f * x*x*x);
  float e = __expf(-2.0f * fabsf(u));
  float t = (1.0f - e) / (1.0f + e);
  t = (u >= 0.f) ? t : -t;
  return 0.5f * x * (1.0f + t);
}

// ---------- K1: weight prep + per-block species histogram ----------
#define W1N (NSm*NDm*NHm)   /* 294912 */
#define W2N (NSm*NHm*NFm)   /* 73728 */
#define WNN (NSm*NFm*NFm)   /* 36864 */
#define WTOT (W1N+W2N+WNN)  /* 405504 */
#define WBLK (WTOT/256)     /* 1584 */
// grid = WBLK + HBLK = 1680
__global__ __launch_bounds__(256) void k_prep(
    const float* __restrict__ W1, const float* __restrict__ W2,
    const float* __restrict__ Wn, const int* __restrict__ sp,
    short* __restrict__ W1t, short* __restrict__ W2t, short* __restrict__ Wnt,
    int* __restrict__ Pcnt){
  int b = blockIdx.x;
  if (b < WBLK){
    int idx = b*256 + threadIdx.x;
    if (idx < W1N){
      int s = idx / (NDm*NHm); int rem = idx - s*NDm*NHm;
      int k = rem / NHm, c = rem - k*NHm;
      W1t[(s*NHm + c)*NDm + k] = f2bf(W1[idx]);
    } else if (idx < W1N + W2N){
      int j = idx - W1N;
      int s = j / (NHm*NFm); int rem = j - s*NHm*NFm;
      int k = rem / NFm, c = rem - k*NFm;
      W2t[(s*NFm + c)*NHm + k] = f2bf(W2[j]);
    } else {
      int j = idx - W1N - W2N;
      int s = j / (NFm*NFm); int rem = j - s*NFm*NFm;
      int k = rem / NFm, c = rem - k*NFm;
      Wnt[(s*NFm + c)*NFm + k] = f2bf(Wn[j]);
    }
  } else {
    // per-block species histogram; LDS atomics only, no pre-zero needed
    __shared__ int h[NSm];
    int t = threadIdx.x;
    if (t < NSm) h[t] = 0;
    __syncthreads();
    int i = (b - WBLK)*256 + t;
    atomicAdd(&h[sp[i]], 1);
    __syncthreads();
    if (t < NSm) Pcnt[(b - WBLK)*NSm + t] = h[t];
  }
}

// ---------- K2: each block redundantly scans Pcnt, then scatters its atoms ----------
// grid = HBLK blocks x 256 threads. Verified algebra (3x derivation):
// slot range of (block b, species s) = [sscan[s]+spre[s,b], +P[b][s]) — disjoint,
// bijective onto [sscan[s], sscan[s+1]). Within-species order arbitrary (per-atom
// MLP values independent of row assignment).
__global__ __launch_bounds__(256) void k_order(const int* __restrict__ sp,
    const int* __restrict__ Pcnt, int* __restrict__ sps, int* __restrict__ order){
  __shared__ int P[HBLK][NSm];
  __shared__ int stot[NSm], spre[NSm], sscan[NSm+1];
  __shared__ int base[NSm], h[NSm];
  int t = threadIdx.x, b = blockIdx.x;
  if (t < HBLK){
    #pragma unroll
    for (int j=0;j<NSm;j++) P[t][j] = Pcnt[t*NSm + j];
  }
  if (t < NSm) h[t] = 0;
  __syncthreads();
  if (t < NSm){
    int tot = 0, pr = 0;
    for (int bb=0; bb<HBLK; bb++){
      if (bb == b) pr = tot;
      tot += P[bb][t];
    }
    stot[t] = tot; spre[t] = pr;
  }
  __syncthreads();
  if (t == 0){
    int r = 0;
    #pragma unroll
    for (int s2=0;s2<NSm;s2++){ sscan[s2] = r; r += stot[s2]; }
    sscan[NSm] = r;
    if (b == 0){
      #pragma unroll
      for (int s2=0;s2<=NSm;s2++) sps[s2] = sscan[s2];
    }
  }
  __syncthreads();
  if (t < NSm) base[t] = sscan[t] + spre[t];
  __syncthreads();
  int i = b*256 + t;
  int s = sp[i];
  int lr = atomicAdd(&h[s], 1);
  order[base[s] + lr] = i;
}

// ---------- fused per-species MLP + epilogue A + LDS-staged nd4 epilogue ----------
// (R12-verified, verbatim)
__global__ __launch_bounds__(256) void k_mlp(
    const float* __restrict__ X, const int* __restrict__ order,
    const int* __restrict__ sps,
    const short* __restrict__ W1t, const short* __restrict__ W2t,
    const short* __restrict__ Wnt, const float* __restrict__ Wf,
    float* __restrict__ pre, float* __restrict__ nd4){
  const int s = blockIdx.y;
  const int s0 = sps[s];
  const int cnt = sps[s+1] - s0;
  const int row0 = blockIdx.x * 64;
  if (row0 >= cnt) return;

  __shared__ short Hs[64][200];     // 25.6 KB
  __shared__ short Is[64][104];     // 13.3 KB
  __shared__ short Ws[19968];       // 39.9 KB staging buffer (aliased as NL below)
  __shared__ int aids[64];

  const int tid = threadIdx.x;
  if (tid < 64){
    int r = row0 + tid;
    aids[tid] = order[s0 + ((r < cnt) ? r : 0)];
  }
  __syncthreads();

  const int wave = tid >> 6, lane = tid & 63;
  const int lrow = lane & 15, quad = lane >> 4;
  const int arow = wave*16 + lrow;
  const float* xrow = X + (size_t)aids[arow]*NDm + quad*8;

  // preload & convert all A fragments (GEMM1) up front
  short8 afs[12];
  #pragma unroll
  for (int kb=0; kb<12; kb++){
    const float* p = xrow + kb*32;
    #pragma unroll
    for (int j=0;j<8;j++) afs[kb][j] = f2bf(p[j]);
  }

  // ---- GEMM1: [64,384]@[384,192]; 4 staged chunks of K=96
  const short* W1s = W1t + (size_t)s*NHm*NDm;
  float4v acc[12];
  #pragma unroll
  for (int i=0;i<12;i++){ acc[i][0]=0.f; acc[i][1]=0.f; acc[i][2]=0.f; acc[i][3]=0.f; }
  for (int kc=0; kc<4; kc++){
    __syncthreads();
    for (int e = tid; e < 192*12; e += 256){   // 192 cols x 12 short8 units
      int c = e / 12, u = e - c*12;
      *(short8*)(&Ws[c*104 + u*8]) = *(const short8*)(W1s + c*NDm + kc*96 + u*8);
    }
    __syncthreads();
    #pragma unroll
    for (int kb3=0; kb3<3; kb3++){
      short8 af = afs[kc*3 + kb3];
      #pragma unroll
      for (int ct=0; ct<12; ct++){
        short8 bfb = *(const short8*)(&Ws[(ct*16 + lrow)*104 + kb3*32 + quad*8]);
        acc[ct] = __builtin_amdgcn_mfma_f32_16x16x32_bf16(af, bfb, acc[ct], 0,0,0);
      }
    }
  }
  // gelu -> Hs (wave-private rows, no barrier)
  #pragma unroll
  for (int ct=0; ct<12; ct++){
    #pragma unroll
    for (int r=0;r<4;r++){
      Hs[wave*16 + quad*4 + r][ct*16 + lrow] = f2bf(gelu_t(acc[ct][r]));
    }
  }

  // ---- GEMM2: [64,192]@[192,96]; stage whole W2 once
  const short* W2s = W2t + (size_t)s*NFm*NHm;
  float4v acc2[6];
  #pragma unroll
  for (int i=0;i<6;i++){ acc2[i][0]=0.f; acc2[i][1]=0.f; acc2[i][2]=0.f; acc2[i][3]=0.f; }
  __syncthreads();
  for (int e = tid; e < 96*24; e += 256){      // 96 cols x 24 short8 units (K=192)
    int c = e / 24, u = e - c*24;
    *(short8*)(&Ws[c*200 + u*8]) = *(const short8*)(W2s + c*NHm + u*8);
  }
  __syncthreads();
  for (int kb=0; kb<6; kb++){
    short8 af2 = *(const short8*)(&Hs[wave*16 + lrow][kb*32 + quad*8]);
    #pragma unroll
    for (int ct=0; ct<6; ct++){
      short8 bfb = *(const short8*)(&Ws[(ct*16 + lrow)*200 + kb*32 + quad*8]);
      acc2[ct] = __builtin_amdgcn_mfma_f32_16x16x32_bf16(af2, bfb, acc2[ct], 0,0,0);
    }
  }
  // internal -> Is (wave-private)
  #pragma unroll
  for (int ct=0; ct<6; ct++){
    #pragma unroll
    for (int r=0;r<4;r++){
      Is[wave*16 + quad*4 + r][ct*16 + lrow] = f2bf(acc2[ct][r]);
    }
  }

  // ---- epilogue A (verified): pre = dot(internal_row, Wf[s][0:96])
  {
    float pr[4] = {0.f,0.f,0.f,0.f};
    #pragma unroll
    for (int ct=0; ct<6; ct++){
      float wv = Wf[s*2*NFm + ct*16 + lrow];
      #pragma unroll
      for (int r=0;r<4;r++) pr[r] += acc2[ct][r] * wv;
    }
    #pragma unroll
    for (int m=1; m<16; m<<=1){
      #pragma unroll
      for (int r=0;r<4;r++) pr[r] += __shfl_xor(pr[r], m, 64);
    }
    if (lrow == 0){
      #pragma unroll
      for (int r=0;r<4;r++){
        int row = wave*16 + quad*4 + r;
        if (row0 + row < cnt) pre[aids[row]] = pr[r];
      }
    }
  }

  // ---- GEMM3: [64,96]@[96,96]; stage whole Wn once
  const short* Wns = Wnt + (size_t)s*NFm*NFm;
  float4v acc3[6];
  #pragma unroll
  for (int i=0;i<6;i++){ acc3[i][0]=0.f; acc3[i][1]=0.f; acc3[i][2]=0.f; acc3[i][3]=0.f; }
  __syncthreads();
  for (int e = tid; e < 96*12; e += 256){      // 96 cols x 12 short8 units (K=96)
    int c = e / 12, u = e - c*12;
    *(short8*)(&Ws[c*104 + u*8]) = *(const short8*)(Wns + c*NFm + u*8);
  }
  __syncthreads();
  for (int kb=0; kb<3; kb++){
    short8 af3 = *(const short8*)(&Is[wave*16 + lrow][kb*32 + quad*8]);
    #pragma unroll
    for (int ct=0; ct<6; ct++){
      short8 bfb = *(const short8*)(&Ws[(ct*16 + lrow)*104 + kb*32 + quad*8]);
      acc3[ct] = __builtin_amdgcn_mfma_f32_16x16x32_bf16(af3, bfb, acc3[ct], 0,0,0);
    }
  }

  // ---- epilogue B (LDS-staged, R12-verified): nd4[a][t2] = dot(nbr_row, Wf[t2][F:2F])
  {
    float* NL = (float*)Ws;            // Ws dead after GEMM3 reads (barrier below)
    __syncthreads();                   // all waves done reading Ws
    #pragma unroll
    for (int ct=0; ct<6; ct++){
      #pragma unroll
      for (int r=0;r<4;r++){
        NL[(wave*16 + quad*4 + r)*97 + ct*16 + lrow] = acc3[ct][r];
      }
    }
    __syncthreads();
    int row = tid >> 2, t2 = tid & 3;
    if (row0 + row < cnt){
      const float* wfp = Wf + t2*2*NFm + NFm;
      const float* nlr = NL + row*97;
      float a4 = 0.f;
      #pragma unroll 8
      for (int j=0;j<NFm;j++) a4 += nlr[j] * wfp[j];
      nd4[(size_t)aids[row]*4 + t2] = a4;
    }
  }
}

// ---------- K-eacc: edge accumulate via full-mrg LDS privatization (R8-verified) ----------
__global__ __launch_bounds__(1024) void k_eacc(const int* __restrict__ ai,
    const float* __restrict__ dist, const float* __restrict__ pref,
    const float* __restrict__ fac, const int* __restrict__ sp,
    const float* __restrict__ nd4, float* __restrict__ part){
  __shared__ float acc[NATOMS];    // 96 KB
  const int t = threadIdx.x, b = blockIdx.x;
  #pragma unroll
  for (int k=0;k<NATOMS/1024;k++) acc[k*1024 + t] = 0.f;   // 24 stores
  __syncthreads();
  const float p = pref[0], fc = fac[0];
  const int base = b*EPB;
  #pragma unroll
  for (int k=0;k<EPB/1024;k++){    // 3 edges/thread, coalesced
    int e = base + k*1024 + t;
    int i0 = ai[e];
    int i1 = ai[NEe + e];
    float d = dist[e];
    int s0 = sp[i0], s1 = sp[i1];
    float4v n1v = *(const float4v*)(nd4 + (size_t)i1*4);
    float4v n0v = *(const float4v*)(nd4 + (size_t)i0*4);
    float x = (CUTOFF_ - d) * (1.0f/CUTOFF_);
    x = fminf(fmaxf(x, 0.f), 1.f);
    float sc = x*x*x*(x*(6.f*x - 15.f) + 10.f);
    float w = p*p * expf(-fc*fc*d) * sc;
    float a1 = (s0 < 2) ? ((s0 == 0) ? n1v[0] : n1v[1]) : ((s0 == 2) ? n1v[2] : n1v[3]);
    float a0 = (s1 < 2) ? ((s1 == 0) ? n0v[0] : n0v[1]) : ((s1 == 2) ? n0v[2] : n0v[3]);
    atomicAdd(&acc[i0], w * a1);
    atomicAdd(&acc[i1], w * a0);
  }
  __syncthreads();
  float* dst = part + (size_t)b*NATOMS;
  for (int k=t; k<NATOMS/4; k+=1024){            // 6 x float4 stores, coalesced
    *(float4v*)(dst + k*4) = *(const float4v*)(&acc[k*4]);
  }
}

// ---------- per-molecule: 256-partial reduce + charge redistribution (R8-verified) ----------
__global__ __launch_bounds__(128) void k_final(const float* __restrict__ pre,
    const float* __restrict__ part, const int* __restrict__ sp,
    const float* __restrict__ tc, float* __restrict__ out){
  __shared__ float red[128];
  int mol = blockIdx.x, t = threadIdx.x;
  float pch = 0.f; int s = 0;
  if (t < NAm){
    int a = mol*NAm + t;
    s = sp[a];
    float m = 0.f;
    #pragma unroll 8
    for (int b=0; b<PBLK; b++) m += part[(size_t)b*NATOMS + a];
    pch = pre[a] + m;
  }
  red[t] = (t < NAm) ? pch : 0.f;
  __syncthreads();
  for (int o=64; o>0; o>>=1){
    if (t < o) red[t] += red[t + o];
    __syncthreads();
  }
  float sum = red[0];
  if (t < NAm){
    out[mol*NAm + t] = (float)s;                       // species as float
    out[NATOMS + mol*NAm + t] = pch + (tc[mol] - sum) * (1.0f/96.0f);  // charges
    out[2*NATOMS + mol*NAm + t] = pch;                 // precharges
  }
}

extern "C" void kernel_launch(void* const* d_in, const int* in_sizes, int n_in,
                              void* d_out, int out_size, void* d_ws, size_t ws_size,
                              hipStream_t stream) {
  const int*   species = (const int*)  d_in[0];
  const float* X       = (const float*)d_in[1];
  const int*   ai      = (const int*)  d_in[2];
  const float* dist    = (const float*)d_in[3];
  const float* tc      = (const float*)d_in[4];
  const float* W1      = (const float*)d_in[5];
  const float* W2      = (const float*)d_in[6];
  const float* Wn      = (const float*)d_in[7];
  const float* Wf      = (const float*)d_in[8];
  const float* pref    = (const float*)d_in[9];
  const float* fac     = (const float*)d_in[10];
  float* out = (float*)d_out;

  char* w = (char*)d_ws;
  auto alloc = [&](size_t bytes)->char*{
    char* p = w; w += (bytes + 255) & ~(size_t)255; return p;
  };
  int*   Pcnt  = (int*)  alloc((size_t)HBLK*NSm*4);
  int*   sps   = (int*)  alloc(64);
  int*   order = (int*)  alloc((size_t)NATOMS*4);
  float* nd4   = (float*)alloc((size_t)NATOMS*4*4);
  float* pre   = (float*)alloc((size_t)NATOMS*4);
  float* part  = (float*)alloc((size_t)PBLK*NATOMS*4);   // 25.2 MB
  short* W1t   = (short*)alloc((size_t)W1N*2);
  short* W2t   = (short*)alloc((size_t)W2N*2);
  short* Wnt   = (short*)alloc((size_t)WNN*2);

  k_prep<<<WBLK + HBLK, 256, 0, stream>>>(W1, W2, Wn, species, W1t, W2t, Wnt, Pcnt);
  k_order<<<HBLK, 256, 0, stream>>>(species, Pcnt, sps, order);
  dim3 g(NATOMS/64, NSm);
  k_mlp<<<g, 256, 0, stream>>>(X, order, sps, W1t, W2t, Wnt, Wf, pre, nd4);
  k_eacc<<<PBLK, 1024, 0, stream>>>(ai, dist, pref, fac, species, nd4, part);
  k_final<<<NBm, 128, 0, stream>>>(pre, part, species, tc, out);
}